// Round 1
// baseline (222.712 us; speedup 1.0000x reference)
//
#include <hip/hip_runtime.h>

#define NF 256        // features
#define NT 4096       // time steps
#define NB 64         // batch
#define CHUNKS 16     // time chunks for partial reduction
#define TPC (NT / CHUNKS)   // 256 time steps per chunk
#define EPS 1e-5f

// ---------------------------------------------------------------------------
// Kernel 1: per (b, chunk) partial sum / sumsq over TPC time steps.
// 256 threads: lane q = tid&63 owns features 4q..4q+3 (one float4 of a row),
// group g = tid>>6 strides over rows. float4 loads -> 1KB/wave coalesced.
// ---------------------------------------------------------------------------
__global__ __launch_bounds__(256) void k_partial(const float* __restrict__ x,
                                                 float* __restrict__ partial) {
    const int blk = blockIdx.x;           // b * CHUNKS + c
    const int b = blk / CHUNKS;
    const int c = blk % CHUNKS;
    const int tid = threadIdx.x;
    const int q = tid & 63;               // float4 slot within a row (f = 4q..4q+3)
    const int g = tid >> 6;               // row group 0..3

    const float4* __restrict__ xrow =
        (const float4*)(x + ((size_t)b * NT + (size_t)c * TPC) * NF);

    float4 s  = {0.f, 0.f, 0.f, 0.f};
    float4 ss = {0.f, 0.f, 0.f, 0.f};
    for (int t = g; t < TPC; t += 4) {
        float4 v = xrow[t * (NF / 4) + q];
        s.x += v.x; s.y += v.y; s.z += v.z; s.w += v.w;
        ss.x = fmaf(v.x, v.x, ss.x);
        ss.y = fmaf(v.y, v.y, ss.y);
        ss.z = fmaf(v.z, v.z, ss.z);
        ss.w = fmaf(v.w, v.w, ss.w);
    }

    __shared__ float4 smS[4][64];
    __shared__ float4 smQ[4][64];
    smS[g][q] = s;
    smQ[g][q] = ss;
    __syncthreads();

    // thread tid = feature f: sum the 4 row-groups (stride-1 LDS reads, no conflict)
    const float* sS = (const float*)smS;
    const float* sQ = (const float*)smQ;
    float sum = sS[0 * NF + tid] + sS[1 * NF + tid] + sS[2 * NF + tid] + sS[3 * NF + tid];
    float sq  = sQ[0 * NF + tid] + sQ[1 * NF + tid] + sQ[2 * NF + tid] + sQ[3 * NF + tid];

    float* p = partial + (size_t)blk * 2 * NF;
    p[tid]      = sum;
    p[NF + tid] = sq;
}

// ---------------------------------------------------------------------------
// Kernel 2: per batch, reduce chunk partials -> mean/std, then the tiny MLP:
//   h     = relu(W1 @ [mean;std] + b1)      (W1: [F, 2F] row-major)
//   alpha = sigmoid(W2 @ h + b2)            (W2: [F, F]  row-major)
// One block per batch, thread f computes h[f] then alpha[f].
// ---------------------------------------------------------------------------
__global__ __launch_bounds__(256) void k_stats_mlp(
    const float* __restrict__ partial,
    const float* __restrict__ W1, const float* __restrict__ b1,
    const float* __restrict__ W2, const float* __restrict__ b2,
    float* __restrict__ alphaA, float* __restrict__ meanA,
    float* __restrict__ invStdA) {
    const int b = blockIdx.x;
    const int f = threadIdx.x;

    float sum = 0.f, sq = 0.f;
    for (int c = 0; c < CHUNKS; ++c) {
        const float* p = partial + (size_t)(b * CHUNKS + c) * 2 * NF;
        sum += p[f];
        sq  += p[NF + f];
    }
    const float mean = sum * (1.0f / NT);
    float var = sq * (1.0f / NT) - mean * mean;
    var = fmaxf(var, 0.0f);
    const float stdv = sqrtf(var + EPS);

    __shared__ float stats[2 * NF];
    __shared__ float h[NF];
    stats[f]      = mean;
    stats[NF + f] = stdv;
    __syncthreads();

    // h[f] = relu(b1[f] + sum_k stats[k] * W1[f][k])   (LDS broadcast reads)
    float acc = b1[f];
    const float* w1r = W1 + (size_t)f * (2 * NF);
    #pragma unroll 8
    for (int k = 0; k < 2 * NF; ++k) acc = fmaf(stats[k], w1r[k], acc);
    h[f] = fmaxf(acc, 0.0f);
    __syncthreads();

    float acc2 = b2[f];
    const float* w2r = W2 + (size_t)f * NF;
    #pragma unroll 8
    for (int k = 0; k < NF; ++k) acc2 = fmaf(h[k], w2r[k], acc2);
    const float alpha = 1.0f / (1.0f + __expf(-acc2));

    alphaA [b * NF + f] = alpha;
    meanA  [b * NF + f] = mean;
    invStdA[b * NF + f] = 1.0f / stdv;
}

// ---------------------------------------------------------------------------
// Kernel 3: elementwise apply, float4-vectorized, grid-stride.
// out = gamma * tanh(alpha * (x - mean) * invstd) + beta
// ---------------------------------------------------------------------------
__device__ __forceinline__ float fast_tanh(float v) {
    // tanh(v) = 1 - 2/(exp(2v)+1); exp inf/0 endpoints give exactly +-1.
    float e = __expf(2.0f * v);
    return 1.0f - 2.0f * __builtin_amdgcn_rcpf(e + 1.0f);
}

__global__ __launch_bounds__(256) void k_apply(
    const float4* __restrict__ x,
    const float4* __restrict__ alpha, const float4* __restrict__ mean,
    const float4* __restrict__ invstd,
    const float4* __restrict__ gamma, const float4* __restrict__ beta,
    float4* __restrict__ out, int total4) {
    const int stride = gridDim.x * blockDim.x;
    for (int idx = blockIdx.x * blockDim.x + threadIdx.x; idx < total4; idx += stride) {
        const int b  = idx >> 18;       // / (NT*NF/4 = 262144)
        const int fq = idx & 63;        // float4 slot within the feature row
        float4 v  = x[idx];
        float4 a4 = alpha [b * 64 + fq];
        float4 m4 = mean  [b * 64 + fq];
        float4 i4 = invstd[b * 64 + fq];
        float4 g4 = gamma[fq];
        float4 t4 = beta [fq];
        float4 o;
        o.x = fmaf(g4.x, fast_tanh(a4.x * (v.x - m4.x) * i4.x), t4.x);
        o.y = fmaf(g4.y, fast_tanh(a4.y * (v.y - m4.y) * i4.y), t4.y);
        o.z = fmaf(g4.z, fast_tanh(a4.z * (v.z - m4.z) * i4.z), t4.z);
        o.w = fmaf(g4.w, fast_tanh(a4.w * (v.w - m4.w) * i4.w), t4.w);
        out[idx] = o;
    }
}

extern "C" void kernel_launch(void* const* d_in, const int* in_sizes, int n_in,
                              void* d_out, int out_size, void* d_ws, size_t ws_size,
                              hipStream_t stream) {
    const float* x     = (const float*)d_in[0];
    const float* gamma = (const float*)d_in[1];
    const float* beta  = (const float*)d_in[2];
    const float* W1    = (const float*)d_in[3];
    const float* b1    = (const float*)d_in[4];
    const float* W2    = (const float*)d_in[5];
    const float* b2    = (const float*)d_in[6];
    float* out = (float*)d_out;

    float* ws      = (float*)d_ws;
    float* partial = ws;                                   // B*CHUNKS*2*F = 2 MB
    float* alphaA  = ws + (size_t)NB * CHUNKS * 2 * NF;    // 64 KB
    float* meanA   = alphaA + NB * NF;                     // 64 KB
    float* invStdA = meanA + NB * NF;                      // 64 KB

    k_partial<<<NB * CHUNKS, 256, 0, stream>>>(x, partial);
    k_stats_mlp<<<NB, 256, 0, stream>>>(partial, W1, b1, W2, b2,
                                        alphaA, meanA, invStdA);
    const int total4 = NB * NT * NF / 4;                   // 16,777,216
    k_apply<<<2048, 256, 0, stream>>>((const float4*)x,
                                      (const float4*)alphaA, (const float4*)meanA,
                                      (const float4*)invStdA,
                                      (const float4*)gamma, (const float4*)beta,
                                      (float4*)out, total4);
}

// Round 3
// 158.474 us; speedup vs baseline: 1.4054x; 1.4054x over previous
//
#include <hip/hip_runtime.h>

#define NF 256        // features
#define NT 4096       // time steps
#define NB 64         // batch
#define CHUNKS 16     // time chunks for partial reduction
#define TPC (NT / CHUNKS)   // 256 time steps per chunk
#define EPS 1e-5f

typedef float vfloat4 __attribute__((ext_vector_type(4)));  // native vector for NT store

// ---------------------------------------------------------------------------
// Kernel 1: per (b, chunk) partial sum / sumsq over TPC time steps.
// ---------------------------------------------------------------------------
__global__ __launch_bounds__(256) void k_partial(const float* __restrict__ x,
                                                 float* __restrict__ partial) {
    const int blk = blockIdx.x;           // b * CHUNKS + c
    const int b = blk / CHUNKS;
    const int c = blk % CHUNKS;
    const int tid = threadIdx.x;
    const int q = tid & 63;               // float4 slot within a row (f = 4q..4q+3)
    const int g = tid >> 6;               // row group 0..3

    const float4* __restrict__ xrow =
        (const float4*)(x + ((size_t)b * NT + (size_t)c * TPC) * NF);

    float4 s  = {0.f, 0.f, 0.f, 0.f};
    float4 ss = {0.f, 0.f, 0.f, 0.f};
    for (int t = g; t < TPC; t += 4) {
        float4 v = xrow[t * (NF / 4) + q];
        s.x += v.x; s.y += v.y; s.z += v.z; s.w += v.w;
        ss.x = fmaf(v.x, v.x, ss.x);
        ss.y = fmaf(v.y, v.y, ss.y);
        ss.z = fmaf(v.z, v.z, ss.z);
        ss.w = fmaf(v.w, v.w, ss.w);
    }

    __shared__ float4 smS[4][64];
    __shared__ float4 smQ[4][64];
    smS[g][q] = s;
    smQ[g][q] = ss;
    __syncthreads();

    const float* sS = (const float*)smS;
    const float* sQ = (const float*)smQ;
    float sum = sS[0 * NF + tid] + sS[1 * NF + tid] + sS[2 * NF + tid] + sS[3 * NF + tid];
    float sq  = sQ[0 * NF + tid] + sQ[1 * NF + tid] + sQ[2 * NF + tid] + sQ[3 * NF + tid];

    float* p = partial + (size_t)blk * 2 * NF;
    p[tid]      = sum;
    p[NF + tid] = sq;
}

// ---------------------------------------------------------------------------
// Kernel 2: reduce partials -> mean/std; tiny MLP -> alpha; fold constants:
//   s = alpha/std,  c = -mean*alpha/std   so  z = x*s + c
// ---------------------------------------------------------------------------
__global__ __launch_bounds__(256) void k_stats_mlp(
    const float* __restrict__ partial,
    const float* __restrict__ W1, const float* __restrict__ b1,
    const float* __restrict__ W2, const float* __restrict__ b2,
    float* __restrict__ sA, float* __restrict__ cA) {
    const int b = blockIdx.x;
    const int f = threadIdx.x;

    float sum = 0.f, sq = 0.f;
    for (int c = 0; c < CHUNKS; ++c) {
        const float* p = partial + (size_t)(b * CHUNKS + c) * 2 * NF;
        sum += p[f];
        sq  += p[NF + f];
    }
    const float mean = sum * (1.0f / NT);
    float var = sq * (1.0f / NT) - mean * mean;
    var = fmaxf(var, 0.0f);
    const float stdv = sqrtf(var + EPS);

    __shared__ float stats[2 * NF];
    __shared__ float h[NF];
    stats[f]      = mean;
    stats[NF + f] = stdv;
    __syncthreads();

    float acc = b1[f];
    const float* w1r = W1 + (size_t)f * (2 * NF);
    #pragma unroll 8
    for (int k = 0; k < 2 * NF; ++k) acc = fmaf(stats[k], w1r[k], acc);
    h[f] = fmaxf(acc, 0.0f);
    __syncthreads();

    float acc2 = b2[f];
    const float* w2r = W2 + (size_t)f * NF;
    #pragma unroll 8
    for (int k = 0; k < NF; ++k) acc2 = fmaf(h[k], w2r[k], acc2);
    const float alpha = 1.0f / (1.0f + __expf(-acc2));

    const float s = alpha / stdv;
    sA[b * NF + f] = s;
    cA[b * NF + f] = -mean * s;
}

// ---------------------------------------------------------------------------
// Kernel 3: elementwise apply. Each block owns a contiguous 8192-float4
// segment of ONE batch -> b and fq loop-invariant; s/c/gamma/beta loaded once.
// out = gamma * tanh(x*s + c) + beta, nontemporal store (keep x in L3).
// ---------------------------------------------------------------------------
__device__ __forceinline__ float fast_tanh(float v) {
    float e = __expf(2.0f * v);                       // inf/0 endpoints -> +-1
    return 1.0f - 2.0f * __builtin_amdgcn_rcpf(e + 1.0f);
}

__global__ __launch_bounds__(256) void k_apply(
    const float4* __restrict__ x,
    const float4* __restrict__ sA, const float4* __restrict__ cA,
    const float4* __restrict__ gamma, const float4* __restrict__ beta,
    float4* __restrict__ out) {
    const int bid = blockIdx.x;
    const int b   = bid >> 5;             // 32 blocks per batch
    const int seg = bid & 31;
    const int tid = threadIdx.x;
    const int fq  = tid & 63;             // float4 slot within feature row

    const float4 s4 = sA[b * 64 + fq];
    const float4 c4 = cA[b * 64 + fq];
    const float4 g4 = gamma[fq];
    const float4 t4 = beta[fq];

    const size_t base = ((size_t)b << 18) + (size_t)seg * 8192 + tid;
    const float4* __restrict__ xp = x + base;
    vfloat4* __restrict__ op = (vfloat4*)(out + base);

    #pragma unroll 4
    for (int k = 0; k < 32; ++k) {
        float4 v = xp[k * 256];
        vfloat4 o;
        o.x = fmaf(g4.x, fast_tanh(fmaf(v.x, s4.x, c4.x)), t4.x);
        o.y = fmaf(g4.y, fast_tanh(fmaf(v.y, s4.y, c4.y)), t4.y);
        o.z = fmaf(g4.z, fast_tanh(fmaf(v.z, s4.z, c4.z)), t4.z);
        o.w = fmaf(g4.w, fast_tanh(fmaf(v.w, s4.w, c4.w)), t4.w);
        __builtin_nontemporal_store(o, &op[k * 256]);
    }
}

extern "C" void kernel_launch(void* const* d_in, const int* in_sizes, int n_in,
                              void* d_out, int out_size, void* d_ws, size_t ws_size,
                              hipStream_t stream) {
    const float* x     = (const float*)d_in[0];
    const float* gamma = (const float*)d_in[1];
    const float* beta  = (const float*)d_in[2];
    const float* W1    = (const float*)d_in[3];
    const float* b1    = (const float*)d_in[4];
    const float* W2    = (const float*)d_in[5];
    const float* b2    = (const float*)d_in[6];
    float* out = (float*)d_out;

    float* ws      = (float*)d_ws;
    float* partial = ws;                                   // B*CHUNKS*2*F = 2 MB
    float* sA      = ws + (size_t)NB * CHUNKS * 2 * NF;    // 64 KB
    float* cA      = sA + NB * NF;                         // 64 KB

    k_partial<<<NB * CHUNKS, 256, 0, stream>>>(x, partial);
    k_stats_mlp<<<NB, 256, 0, stream>>>(partial, W1, b1, W2, b2, sA, cA);
    k_apply<<<NB * 32, 256, 0, stream>>>((const float4*)x,
                                         (const float4*)sA, (const float4*)cA,
                                         (const float4*)gamma, (const float4*)beta,
                                         (float4*)out);
}